// Round 6
// baseline (45.910 us; speedup 1.0000x reference)
//
#include <hip/hip_runtime.h>
#include <hip/hip_bf16.h>
#include <math.h>

#define BB 256
#define PP 100
#define EE 32
#define VV 1000
#define HH 256
#define NFF 33
#define F35 35
#define K1 1120  // 35*E
#define GSCALE 64.0f
#define GINV 0.015625f
#define NROWS (BB * PP)

// fp8 hw conversion availability
#define FP8_HW 0
#if defined(__has_builtin)
#if __has_builtin(__builtin_amdgcn_cvt_pk_f32_fp8) && __has_builtin(__builtin_amdgcn_cvt_pk_fp8_f32)
#undef FP8_HW
#define FP8_HW 1
#endif
#endif

typedef float v2f __attribute__((ext_vector_type(2)));
typedef short bf16x8 __attribute__((ext_vector_type(8)));
typedef float f32x4 __attribute__((ext_vector_type(4)));

__device__ __forceinline__ unsigned char enc_fp8(float x) {
#if FP8_HW
    int pk = __builtin_amdgcn_cvt_pk_fp8_f32(x, 0.f, 0, false);
    return (unsigned char)(pk & 0xFF);
#else
    float a = fabsf(x);
    unsigned int s = (x < 0.f) ? 0x80u : 0u;
    if (a >= 448.f) return (unsigned char)(s | 0x7E);
    if (a < 0.015625f) {
        int m = (int)rintf(a * 512.f);
        if (m > 7) return (unsigned char)(s | 0x08);
        return (unsigned char)(s | (unsigned int)m);
    }
    unsigned int u = __float_as_uint(a);
    u += 0x00080000u;
    int e = (int)(u >> 23) - 127 + 7;
    if (e >= 16) return (unsigned char)(s | 0x7E);
    return (unsigned char)(s | ((unsigned int)e << 3) | ((u >> 20) & 7));
#endif
}

#if !FP8_HW
__device__ __forceinline__ float dec1(unsigned int b) {
    unsigned int s = b >> 7, e = (b >> 3) & 15, m = b & 7;
    float v = e ? __uint_as_float(((e + 120u) << 23) | (m << 20))
                : (float)m * 0.001953125f;
    return s ? -v : v;
}
#endif

__device__ __forceinline__ unsigned short f2bf(float x) {  // RNE f32->bf16
    unsigned int b = __float_as_uint(x);
    return (unsigned short)((b + 0x7FFFu + ((b >> 16) & 1u)) >> 16);
}

// ---------------- k_pre: MFMA GEMM  G[f][v][ch] fp8  +  S01 sums ----------------
// Direct per-lane u32 stores (lane's D = 4 consecutive ch at one v); no LDS, no barriers.
__global__ __launch_bounds__(256) void k_pre(const float* __restrict__ tables,
                                             const float* __restrict__ W1,
                                             unsigned char* __restrict__ G,
                                             float* __restrict__ S01) {
    int bid = blockIdx.x;
    if (bid == NFF * 16) {  // S01 block
        int j = threadIdx.x;
        const float* row = W1 + (size_t)j * K1;
        float s0 = 0.f, s1 = 0.f;
#pragma unroll
        for (int e = 0; e < 32; ++e) { s0 += row[e]; s1 += row[32 + e]; }
        S01[j] = s0;
        S01[256 + j] = s1;
        return;
    }
    int f = bid % NFF;
    int rest = bid / NFF;        // 0..15
    int ctg = rest & 3;          // 64-ch group
    int vblk = rest >> 2;        // 0..3 (~250 v each; clamp-tail writes identical bytes)
    int t = threadIdx.x;
    int l = t & 63, w = t >> 6;
    int lr = l & 15, lg = l >> 4;

    const float* wp = W1 + (size_t)(ctg * 64 + w * 16 + lr) * K1 + 64 + 32 * f + lg * 4;
    float4 wa = *(const float4*)wp;
    float4 wb = *(const float4*)(wp + 16);
    bf16x8 afrag;
    afrag[0] = f2bf(wa.x); afrag[1] = f2bf(wa.y); afrag[2] = f2bf(wa.z); afrag[3] = f2bf(wa.w);
    afrag[4] = f2bf(wb.x); afrag[5] = f2bf(wb.y); afrag[6] = f2bf(wb.z); afrag[7] = f2bf(wb.w);

    const f32x4 cz = {0.f, 0.f, 0.f, 0.f};
    unsigned char* gdst = G + (size_t)(ctg * 64 + w * 16 + lg * 4);
#pragma unroll 4
    for (int vt = 0; vt < 16; ++vt) {
        int v0 = vblk * 250 + vt * 16;
        int v = v0 + lr; if (v > VV - 1) v = VV - 1;  // clamp: duplicate identical stores
        const float* tp = tables + ((size_t)f * VV + v) * EE + lg * 4;
        float4 ta = *(const float4*)tp;
        float4 tb = *(const float4*)(tp + 16);
        bf16x8 bfrag;
        bfrag[0] = f2bf(ta.x); bfrag[1] = f2bf(ta.y); bfrag[2] = f2bf(ta.z); bfrag[3] = f2bf(ta.w);
        bfrag[4] = f2bf(tb.x); bfrag[5] = f2bf(tb.y); bfrag[6] = f2bf(tb.z); bfrag[7] = f2bf(tb.w);
        f32x4 d = __builtin_amdgcn_mfma_f32_16x16x32_bf16(afrag, bfrag, cz, 0, 0, 0);
        unsigned int pk;
#if FP8_HW
        int ipk = __builtin_amdgcn_cvt_pk_fp8_f32(d[0] * GSCALE, d[1] * GSCALE, 0, false);
        ipk = __builtin_amdgcn_cvt_pk_fp8_f32(d[2] * GSCALE, d[3] * GSCALE, ipk, true);
        pk = (unsigned int)ipk;
#else
        pk = (unsigned int)enc_fp8(d[0] * GSCALE) |
             ((unsigned int)enc_fp8(d[1] * GSCALE) << 8) |
             ((unsigned int)enc_fp8(d[2] * GSCALE) << 16) |
             ((unsigned int)enc_fp8(d[3] * GSCALE) << 24);
#endif
        *(unsigned int*)(gdst + ((size_t)f * VV + v) * HH) = pk;
    }
}

// ---------------- k_main: 4 rows/wave, dwordx4 gathers (16 lanes x 16B = one 256B row) ----
// block = 256 thr = 4 waves = 16 rows. lane: rg=lane>>4 (row in wave), li=lane&15 (ch quad16).
__global__ __launch_bounds__(256) void k_main(const float* __restrict__ x,
                                              const unsigned char* __restrict__ G,
                                              const float* __restrict__ S01,
                                              const float* __restrict__ b1,
                                              const float* __restrict__ W2,
                                              const float* __restrict__ b2,
                                              float* __restrict__ logits) {
    __shared__ int sxi[16][NFF];
    __shared__ float sx01[16][2];
    int t = threadIdx.x;
    int rowbase = blockIdx.x * 16;
    for (int k = t; k < 16 * F35; k += 256) {
        int r = k / F35, c = k - r * F35;
        float vv = x[(size_t)(rowbase + r) * F35 + c];
        if (c < 2) sx01[r][c] = vv;
        else sxi[r][c - 2] = (int)vv;
    }
    __syncthreads();
    int lane = t & 63, wave = t >> 6;
    int rg = lane >> 4, li = lane & 15;
    int rloc = wave * 4 + rg;
    v2f ac0 = {0.f, 0.f}, ac1 = {0.f, 0.f}, ac2 = {0.f, 0.f}, ac3 = {0.f, 0.f};
    v2f ac4 = {0.f, 0.f}, ac5 = {0.f, 0.f}, ac6 = {0.f, 0.f}, ac7 = {0.f, 0.f};
#pragma unroll
    for (int f = 0; f < NFF; ++f) {
        int v = sxi[rloc][f];
        uint4 u = *(const uint4*)(G + ((size_t)f * VV + v) * HH + li * 16);
#if FP8_HW
        ac0 += __builtin_amdgcn_cvt_pk_f32_fp8((int)u.x, false);
        ac1 += __builtin_amdgcn_cvt_pk_f32_fp8((int)u.x, true);
        ac2 += __builtin_amdgcn_cvt_pk_f32_fp8((int)u.y, false);
        ac3 += __builtin_amdgcn_cvt_pk_f32_fp8((int)u.y, true);
        ac4 += __builtin_amdgcn_cvt_pk_f32_fp8((int)u.z, false);
        ac5 += __builtin_amdgcn_cvt_pk_f32_fp8((int)u.z, true);
        ac6 += __builtin_amdgcn_cvt_pk_f32_fp8((int)u.w, false);
        ac7 += __builtin_amdgcn_cvt_pk_f32_fp8((int)u.w, true);
#else
        ac0[0] += dec1(u.x & 255u); ac0[1] += dec1((u.x >> 8) & 255u);
        ac1[0] += dec1((u.x >> 16) & 255u); ac1[1] += dec1(u.x >> 24);
        ac2[0] += dec1(u.y & 255u); ac2[1] += dec1((u.y >> 8) & 255u);
        ac3[0] += dec1((u.y >> 16) & 255u); ac3[1] += dec1(u.y >> 24);
        ac4[0] += dec1(u.z & 255u); ac4[1] += dec1((u.z >> 8) & 255u);
        ac5[0] += dec1((u.z >> 16) & 255u); ac5[1] += dec1(u.z >> 24);
        ac6[0] += dec1(u.w & 255u); ac6[1] += dec1((u.w >> 8) & 255u);
        ac7[0] += dec1((u.w >> 16) & 255u); ac7[1] += dec1(u.w >> 24);
#endif
    }
    float x0 = sx01[rloc][0], x1 = sx01[rloc][1];
    int j0 = li * 16;
    float pacc = 0.f;
#define QUAD(q, aclo, achi) {                                              \
    float4 s0v = *(const float4*)(S01 + j0 + (q)*4);                       \
    float4 s1v = *(const float4*)(S01 + 256 + j0 + (q)*4);                 \
    float4 b1v = *(const float4*)(b1 + j0 + (q)*4);                        \
    float4 w2v = *(const float4*)(W2 + j0 + (q)*4);                        \
    float a0 = b1v.x + x0 * s0v.x + x1 * s1v.x + aclo[0] * GINV;           \
    float a1 = b1v.y + x0 * s0v.y + x1 * s1v.y + aclo[1] * GINV;           \
    float a2 = b1v.z + x0 * s0v.z + x1 * s1v.z + achi[0] * GINV;           \
    float a3 = b1v.w + x0 * s0v.w + x1 * s1v.w + achi[1] * GINV;           \
    pacc += fmaxf(a0, 0.f) * w2v.x + fmaxf(a1, 0.f) * w2v.y +              \
            fmaxf(a2, 0.f) * w2v.z + fmaxf(a3, 0.f) * w2v.w; }
    QUAD(0, ac0, ac1); QUAD(1, ac2, ac3); QUAD(2, ac4, ac5); QUAD(3, ac6, ac7);
#undef QUAD
    pacc += __shfl_xor(pacc, 1, 64);
    pacc += __shfl_xor(pacc, 2, 64);
    pacc += __shfl_xor(pacc, 4, 64);
    pacc += __shfl_xor(pacc, 8, 64);
    if (li == 0) logits[rowbase + rloc] = pacc + b2[0];
}

// ---------------- Fallback (small ws): direct fp32 compute of logits ----------------
__global__ void k_direct(const float* __restrict__ x,
                         const float* __restrict__ tables,
                         const float* __restrict__ W1,
                         const float* __restrict__ b1,
                         const float* __restrict__ W2,
                         const float* __restrict__ b2,
                         float* __restrict__ logits) {
    int r = blockIdx.x;
    int j = threadIdx.x;
    __shared__ int sidx[NFF];
    __shared__ float sx[2];
    __shared__ float red[256];
    const float* xr = x + (size_t)r * F35;
    if (j < 2) sx[j] = xr[j];
    if (j >= 2 && j < F35) sidx[j - 2] = (int)xr[j];
    __syncthreads();
    const float* w = W1 + (size_t)j * K1;
    float acc = b1[j];
    float s0 = 0.f, s1 = 0.f;
#pragma unroll
    for (int e = 0; e < 32; ++e) { s0 += w[e]; s1 += w[32 + e]; }
    acc += sx[0] * s0 + sx[1] * s1;
    for (int f = 0; f < NFF; ++f) {
        const float* tr = tables + ((size_t)f * VV + sidx[f]) * EE;
        const float* wf = w + 64 + 32 * f;
#pragma unroll
        for (int e = 0; e < 32; ++e) acc += tr[e] * wf[e];
    }
    float h = fmaxf(acc, 0.f);
    red[j] = h * W2[j];
    __syncthreads();
#pragma unroll
    for (int s = 128; s > 0; s >>= 1) {
        if (j < s) red[j] += red[j + s];
        __syncthreads();
    }
    if (j == 0) logits[r] = red[0] + b2[0];
}

// ---------------- softmax over P per b (in-place on d_out) ----------------
__global__ void k_softmax(float* __restrict__ io) {
    int b = blockIdx.x;
    int t = threadIdx.x;  // 128
    __shared__ float buf[128];
    float v = (t < PP) ? io[(size_t)b * PP + t] : -INFINITY;
    buf[t] = v;
    __syncthreads();
#pragma unroll
    for (int s = 64; s > 0; s >>= 1) {
        if (t < s) buf[t] = fmaxf(buf[t], buf[t + s]);
        __syncthreads();
    }
    float m = buf[0];
    __syncthreads();
    float e = (t < PP) ? __expf(v - m) : 0.f;
    buf[t] = e;
    __syncthreads();
#pragma unroll
    for (int s = 64; s > 0; s >>= 1) {
        if (t < s) buf[t] += buf[t + s];
        __syncthreads();
    }
    float denom = buf[0];
    if (t < PP) io[(size_t)b * PP + t] = e / denom;
}

extern "C" void kernel_launch(void* const* d_in, const int* in_sizes, int n_in,
                              void* d_out, int out_size, void* d_ws, size_t ws_size,
                              hipStream_t stream) {
    const float* x      = (const float*)d_in[0];
    const float* tables = (const float*)d_in[1];
    const float* W1     = (const float*)d_in[2];
    const float* b1     = (const float*)d_in[3];
    const float* W2     = (const float*)d_in[4];
    const float* b2     = (const float*)d_in[5];
    float* out = (float*)d_out;

    const size_t gbytes = (size_t)NFF * VV * HH;  // 8,448,000 fp8
    const size_t need = gbytes + 2048;

    if (ws_size >= need) {
        char* ws = (char*)d_ws;
        unsigned char* G = (unsigned char*)ws;
        float* S01 = (float*)(ws + gbytes);
        hipLaunchKernelGGL(k_pre, dim3(NFF * 16 + 1), dim3(256), 0, stream, tables, W1, G, S01);
        hipLaunchKernelGGL(k_main, dim3(NROWS / 16), dim3(256), 0, stream,
                           x, G, S01, b1, W2, b2, out);
    } else {
        hipLaunchKernelGGL(k_direct, dim3(NROWS), dim3(256), 0, stream,
                           x, tables, W1, b1, W2, b2, out);
    }
    hipLaunchKernelGGL(k_softmax, dim3(BB), dim3(128), 0, stream, out);
}

// Round 7
// 43.608 us; speedup vs baseline: 1.0528x; 1.0528x over previous
//
#include <hip/hip_runtime.h>
#include <hip/hip_bf16.h>
#include <math.h>

#define BB 256
#define PP 100
#define EE 32
#define VV 1000
#define HH 256
#define NFF 33
#define F35 35
#define K1 1120  // 35*E
#define GSCALE 64.0f
#define GINV 0.015625f
#define NROWS (BB * PP)
#define HALF_BYTES ((size_t)NFF * VV * 128)  // 4,224,000 per 128-ch half

// fp8 hw conversion availability
#define FP8_HW 0
#if defined(__has_builtin)
#if __has_builtin(__builtin_amdgcn_cvt_pk_f32_fp8) && __has_builtin(__builtin_amdgcn_cvt_pk_fp8_f32)
#undef FP8_HW
#define FP8_HW 1
#endif
#endif

typedef float v2f __attribute__((ext_vector_type(2)));
typedef short bf16x8 __attribute__((ext_vector_type(8)));
typedef float f32x4 __attribute__((ext_vector_type(4)));

__device__ __forceinline__ unsigned char enc_fp8(float x) {
#if FP8_HW
    int pk = __builtin_amdgcn_cvt_pk_fp8_f32(x, 0.f, 0, false);
    return (unsigned char)(pk & 0xFF);
#else
    float a = fabsf(x);
    unsigned int s = (x < 0.f) ? 0x80u : 0u;
    if (a >= 448.f) return (unsigned char)(s | 0x7E);
    if (a < 0.015625f) {
        int m = (int)rintf(a * 512.f);
        if (m > 7) return (unsigned char)(s | 0x08);
        return (unsigned char)(s | (unsigned int)m);
    }
    unsigned int u = __float_as_uint(a);
    u += 0x00080000u;
    int e = (int)(u >> 23) - 127 + 7;
    if (e >= 16) return (unsigned char)(s | 0x7E);
    return (unsigned char)(s | ((unsigned int)e << 3) | ((u >> 20) & 7));
#endif
}

#if !FP8_HW
__device__ __forceinline__ float dec1(unsigned int b) {
    unsigned int s = b >> 7, e = (b >> 3) & 15, m = b & 7;
    float v = e ? __uint_as_float(((e + 120u) << 23) | (m << 20))
                : (float)m * 0.001953125f;
    return s ? -v : v;
}
#endif

__device__ __forceinline__ unsigned short f2bf(float x) {  // RNE f32->bf16
    unsigned int b = __float_as_uint(x);
    return (unsigned short)((b + 0x7FFFu + ((b >> 16) & 1u)) >> 16);
}

// ---------------- k_pre: MFMA GEMM -> G[half][f][v][128ch] fp8 + S01 sums ----------------
__global__ __launch_bounds__(256) void k_pre(const float* __restrict__ tables,
                                             const float* __restrict__ W1,
                                             unsigned char* __restrict__ G,
                                             float* __restrict__ S01) {
    int bid = blockIdx.x;
    if (bid == NFF * 16) {  // S01 block
        int j = threadIdx.x;
        const float* row = W1 + (size_t)j * K1;
        float s0 = 0.f, s1 = 0.f;
#pragma unroll
        for (int e = 0; e < 32; ++e) { s0 += row[e]; s1 += row[32 + e]; }
        S01[j] = s0;
        S01[256 + j] = s1;
        return;
    }
    int f = bid % NFF;
    int rest = bid / NFF;        // 0..15
    int ctg = rest & 3;          // 64-ch group
    int vblk = rest >> 2;        // 0..3 (~250 v each; clamp-tail writes identical bytes)
    int t = threadIdx.x;
    int l = t & 63, w = t >> 6;
    int lr = l & 15, lg = l >> 4;

    const float* wp = W1 + (size_t)(ctg * 64 + w * 16 + lr) * K1 + 64 + 32 * f + lg * 4;
    float4 wa = *(const float4*)wp;
    float4 wb = *(const float4*)(wp + 16);
    bf16x8 afrag;
    afrag[0] = f2bf(wa.x); afrag[1] = f2bf(wa.y); afrag[2] = f2bf(wa.z); afrag[3] = f2bf(wa.w);
    afrag[4] = f2bf(wb.x); afrag[5] = f2bf(wb.y); afrag[6] = f2bf(wb.z); afrag[7] = f2bf(wb.w);

    const f32x4 cz = {0.f, 0.f, 0.f, 0.f};
    // channel j = ctg*64 + w*16 + lg*4 ; half = ctg>>1 ; in-half offset = (ctg&1)*64 + w*16 + lg*4
    unsigned char* gdst = G + (size_t)(ctg >> 1) * HALF_BYTES
                            + (size_t)((ctg & 1) * 64 + w * 16 + lg * 4);
#pragma unroll 4
    for (int vt = 0; vt < 16; ++vt) {
        int v0 = vblk * 250 + vt * 16;
        int v = v0 + lr; if (v > VV - 1) v = VV - 1;  // clamp: duplicate identical stores
        const float* tp = tables + ((size_t)f * VV + v) * EE + lg * 4;
        float4 ta = *(const float4*)tp;
        float4 tb = *(const float4*)(tp + 16);
        bf16x8 bfrag;
        bfrag[0] = f2bf(ta.x); bfrag[1] = f2bf(ta.y); bfrag[2] = f2bf(ta.z); bfrag[3] = f2bf(ta.w);
        bfrag[4] = f2bf(tb.x); bfrag[5] = f2bf(tb.y); bfrag[6] = f2bf(tb.z); bfrag[7] = f2bf(tb.w);
        f32x4 d = __builtin_amdgcn_mfma_f32_16x16x32_bf16(afrag, bfrag, cz, 0, 0, 0);
        unsigned int pk;
#if FP8_HW
        int ipk = __builtin_amdgcn_cvt_pk_fp8_f32(d[0] * GSCALE, d[1] * GSCALE, 0, false);
        ipk = __builtin_amdgcn_cvt_pk_fp8_f32(d[2] * GSCALE, d[3] * GSCALE, ipk, true);
        pk = (unsigned int)ipk;
#else
        pk = (unsigned int)enc_fp8(d[0] * GSCALE) |
             ((unsigned int)enc_fp8(d[1] * GSCALE) << 8) |
             ((unsigned int)enc_fp8(d[2] * GSCALE) << 16) |
             ((unsigned int)enc_fp8(d[3] * GSCALE) << 24);
#endif
        *(unsigned int*)(gdst + ((size_t)f * VV + v) * 128) = pk;
    }
}

// ---------------- k_main: XCD-local half-gather ----------------
// half = bid&1 (round-robin XCD=bid%8 -> even XCDs see half0 only, odd half1: 4.2MB L2-resident).
// wave = 8 rows x 8 lanes; per (row,f): one dwordx4 x 8 lanes = exactly one 128B line, fully used.
__global__ __launch_bounds__(256) void k_main(const float* __restrict__ x,
                                              const unsigned char* __restrict__ G,
                                              const float* __restrict__ S01,
                                              const float* __restrict__ b1,
                                              const float* __restrict__ W2,
                                              float* __restrict__ part) {
    int s = blockIdx.x & 1;
    int rowbase = (blockIdx.x >> 1) * 32;
    __shared__ int sxi[32][NFF];
    __shared__ float sx01[32][2];
    int t = threadIdx.x;
    for (int k = t; k < 32 * F35; k += 256) {
        int r = k / F35, c = k - r * F35;
        float vv = x[(size_t)(rowbase + r) * F35 + c];
        if (c < 2) sx01[r][c] = vv;
        else sxi[r][c - 2] = (int)vv;
    }
    __syncthreads();
    int lane = t & 63, wave = t >> 6;
    int rg = lane >> 3, li = lane & 7;
    int rloc = wave * 8 + rg;
    const unsigned char* Gs = G + (size_t)s * HALF_BYTES + li * 16;
    v2f ac0 = {0.f, 0.f}, ac1 = {0.f, 0.f}, ac2 = {0.f, 0.f}, ac3 = {0.f, 0.f};
    v2f ac4 = {0.f, 0.f}, ac5 = {0.f, 0.f}, ac6 = {0.f, 0.f}, ac7 = {0.f, 0.f};
#pragma unroll
    for (int f = 0; f < NFF; ++f) {
        int v = sxi[rloc][f];
        uint4 u = *(const uint4*)(Gs + ((size_t)f * VV + v) * 128);
#if FP8_HW
        ac0 += __builtin_amdgcn_cvt_pk_f32_fp8((int)u.x, false);
        ac1 += __builtin_amdgcn_cvt_pk_f32_fp8((int)u.x, true);
        ac2 += __builtin_amdgcn_cvt_pk_f32_fp8((int)u.y, false);
        ac3 += __builtin_amdgcn_cvt_pk_f32_fp8((int)u.y, true);
        ac4 += __builtin_amdgcn_cvt_pk_f32_fp8((int)u.z, false);
        ac5 += __builtin_amdgcn_cvt_pk_f32_fp8((int)u.z, true);
        ac6 += __builtin_amdgcn_cvt_pk_f32_fp8((int)u.w, false);
        ac7 += __builtin_amdgcn_cvt_pk_f32_fp8((int)u.w, true);
#else
        ac0[0] += dec1(u.x & 255u); ac0[1] += dec1((u.x >> 8) & 255u);
        ac1[0] += dec1((u.x >> 16) & 255u); ac1[1] += dec1(u.x >> 24);
        ac2[0] += dec1(u.y & 255u); ac2[1] += dec1((u.y >> 8) & 255u);
        ac3[0] += dec1((u.y >> 16) & 255u); ac3[1] += dec1(u.y >> 24);
        ac4[0] += dec1(u.z & 255u); ac4[1] += dec1((u.z >> 8) & 255u);
        ac5[0] += dec1((u.z >> 16) & 255u); ac5[1] += dec1(u.z >> 24);
        ac6[0] += dec1(u.w & 255u); ac6[1] += dec1((u.w >> 8) & 255u);
        ac7[0] += dec1((u.w >> 16) & 255u); ac7[1] += dec1(u.w >> 24);
#endif
    }
    float x0 = sx01[rloc][0], x1 = sx01[rloc][1];
    int j0 = s * 128 + li * 16;
    float pacc = 0.f;
#define QUAD(q, aclo, achi) {                                              \
    float4 s0v = *(const float4*)(S01 + j0 + (q)*4);                       \
    float4 s1v = *(const float4*)(S01 + 256 + j0 + (q)*4);                 \
    float4 b1v = *(const float4*)(b1 + j0 + (q)*4);                        \
    float4 w2v = *(const float4*)(W2 + j0 + (q)*4);                        \
    float a0 = b1v.x + x0 * s0v.x + x1 * s1v.x + aclo[0] * GINV;           \
    float a1 = b1v.y + x0 * s0v.y + x1 * s1v.y + aclo[1] * GINV;           \
    float a2 = b1v.z + x0 * s0v.z + x1 * s1v.z + achi[0] * GINV;           \
    float a3 = b1v.w + x0 * s0v.w + x1 * s1v.w + achi[1] * GINV;           \
    pacc += fmaxf(a0, 0.f) * w2v.x + fmaxf(a1, 0.f) * w2v.y +              \
            fmaxf(a2, 0.f) * w2v.z + fmaxf(a3, 0.f) * w2v.w; }
    QUAD(0, ac0, ac1); QUAD(1, ac2, ac3); QUAD(2, ac4, ac5); QUAD(3, ac6, ac7);
#undef QUAD
    pacc += __shfl_xor(pacc, 1, 64);
    pacc += __shfl_xor(pacc, 2, 64);
    pacc += __shfl_xor(pacc, 4, 64);
    if (li == 0) part[(size_t)s * NROWS + rowbase + rloc] = pacc;
}

// ---------------- softmax over P per b: sums the 2 half-partials ----------------
__global__ void k_softmax2(const float* __restrict__ part, const float* __restrict__ b2,
                           float* __restrict__ io) {
    int b = blockIdx.x;
    int t = threadIdx.x;  // 128
    __shared__ float buf[128];
    float lg = -INFINITY;
    if (t < PP) {
        int r = b * PP + t;
        lg = part[r] + part[NROWS + r] + b2[0];
    }
    buf[t] = lg;
    __syncthreads();
#pragma unroll
    for (int s = 64; s > 0; s >>= 1) {
        if (t < s) buf[t] = fmaxf(buf[t], buf[t + s]);
        __syncthreads();
    }
    float m = buf[0];
    __syncthreads();
    float e = (t < PP) ? __expf(lg - m) : 0.f;
    buf[t] = e;
    __syncthreads();
#pragma unroll
    for (int s = 64; s > 0; s >>= 1) {
        if (t < s) buf[t] += buf[t + s];
        __syncthreads();
    }
    float denom = buf[0];
    if (t < PP) io[(size_t)b * PP + t] = e / denom;
}

// ---------------- Fallback (small ws): direct fp32 compute of logits ----------------
__global__ void k_direct(const float* __restrict__ x,
                         const float* __restrict__ tables,
                         const float* __restrict__ W1,
                         const float* __restrict__ b1,
                         const float* __restrict__ W2,
                         const float* __restrict__ b2,
                         float* __restrict__ logits) {
    int r = blockIdx.x;
    int j = threadIdx.x;
    __shared__ int sidx[NFF];
    __shared__ float sx[2];
    __shared__ float red[256];
    const float* xr = x + (size_t)r * F35;
    if (j < 2) sx[j] = xr[j];
    if (j >= 2 && j < F35) sidx[j - 2] = (int)xr[j];
    __syncthreads();
    const float* w = W1 + (size_t)j * K1;
    float acc = b1[j];
    float s0 = 0.f, s1 = 0.f;
#pragma unroll
    for (int e = 0; e < 32; ++e) { s0 += w[e]; s1 += w[32 + e]; }
    acc += sx[0] * s0 + sx[1] * s1;
    for (int f = 0; f < NFF; ++f) {
        const float* tr = tables + ((size_t)f * VV + sidx[f]) * EE;
        const float* wf = w + 64 + 32 * f;
#pragma unroll
        for (int e = 0; e < 32; ++e) acc += tr[e] * wf[e];
    }
    float h = fmaxf(acc, 0.f);
    red[j] = h * W2[j];
    __syncthreads();
#pragma unroll
    for (int s = 128; s > 0; s >>= 1) {
        if (j < s) red[j] += red[j + s];
        __syncthreads();
    }
    if (j == 0) logits[r] = red[0] + b2[0];
}

__global__ void k_softmax_inplace(float* __restrict__ io) {
    int b = blockIdx.x;
    int t = threadIdx.x;  // 128
    __shared__ float buf[128];
    float v = (t < PP) ? io[(size_t)b * PP + t] : -INFINITY;
    buf[t] = v;
    __syncthreads();
#pragma unroll
    for (int s = 64; s > 0; s >>= 1) {
        if (t < s) buf[t] = fmaxf(buf[t], buf[t + s]);
        __syncthreads();
    }
    float m = buf[0];
    __syncthreads();
    float e = (t < PP) ? __expf(v - m) : 0.f;
    buf[t] = e;
    __syncthreads();
#pragma unroll
    for (int s = 64; s > 0; s >>= 1) {
        if (t < s) buf[t] += buf[t + s];
        __syncthreads();
    }
    float denom = buf[0];
    if (t < PP) io[(size_t)b * PP + t] = e / denom;
}

extern "C" void kernel_launch(void* const* d_in, const int* in_sizes, int n_in,
                              void* d_out, int out_size, void* d_ws, size_t ws_size,
                              hipStream_t stream) {
    const float* x      = (const float*)d_in[0];
    const float* tables = (const float*)d_in[1];
    const float* W1     = (const float*)d_in[2];
    const float* b1     = (const float*)d_in[3];
    const float* W2     = (const float*)d_in[4];
    const float* b2     = (const float*)d_in[5];
    float* out = (float*)d_out;

    const size_t gbytes = 2 * HALF_BYTES;               // 8,448,000 fp8
    const size_t part_off = gbytes;                     // 256B-aligned (8448000 = 33000*256)
    const size_t s01_off = part_off + (size_t)2 * NROWS * sizeof(float);
    const size_t need = s01_off + 2048;

    if (ws_size >= need) {
        char* ws = (char*)d_ws;
        unsigned char* G = (unsigned char*)ws;
        float* part = (float*)(ws + part_off);
        float* S01 = (float*)(ws + s01_off);
        hipLaunchKernelGGL(k_pre, dim3(NFF * 16 + 1), dim3(256), 0, stream, tables, W1, G, S01);
        hipLaunchKernelGGL(k_main, dim3((NROWS / 32) * 2), dim3(256), 0, stream,
                           x, G, S01, b1, W2, part);
        hipLaunchKernelGGL(k_softmax2, dim3(BB), dim3(128), 0, stream, part, b2, out);
    } else {
        hipLaunchKernelGGL(k_direct, dim3(NROWS), dim3(256), 0, stream,
                           x, tables, W1, b1, W2, b2, out);
        hipLaunchKernelGGL(k_softmax_inplace, dim3(BB), dim3(128), 0, stream, out);
    }
}